// Round 2
// baseline (861.998 us; speedup 1.0000x reference)
//
#include <hip/hip_runtime.h>
#include <hip/hip_bf16.h>

// LinearMPC PGD, round 2: H stationary in VGPRs, paired-block column split.
// 256 blocks x 512 thr. Team = 16 batch rows; block half h owns cols [h*256,+256).
// Each block holds its 256 H-rows as bf16 MFMA B-fragments in registers (128 VGPR/wave)
// -> zero per-iteration H traffic. u-halves exchanged via agent-scope (sc1) atomics.

typedef unsigned short u16t;
typedef __attribute__((ext_vector_type(8))) short short8;
typedef __attribute__((ext_vector_type(4))) float floatx4;

__device__ __forceinline__ u16t f32_to_bf16(float x) {
    unsigned int u = __builtin_bit_cast(unsigned int, x);
    u = (u + 0x7FFFu + ((u >> 16) & 1u)) >> 16;   // RNE
    return (u16t)u;
}

__global__ void init_flags_kernel(int* flags) {
    flags[threadIdx.x * 16] = 0;     // 256 threads, one flag per block, 64B apart
}

__global__ __launch_bounds__(512, 2)
void pgd_pair_kernel(const float* __restrict__ xref,      // [2048][65][8]
                     const float* __restrict__ H,         // [512][512] fp32
                     const float* __restrict__ Phi,       // [65][8][8]
                     const float* __restrict__ Q,         // [8][8]
                     float* __restrict__ out,             // [2048][512]
                     int* __restrict__ flags,             // [256*16]
                     u16t* __restrict__ ubuf)             // [256][2][4096]
{
    __shared__ __align__(16) u16t u_bf[16][520];
    __shared__ float W[64][64];

    const int tid  = threadIdx.x;
    const int lane = tid & 63;
    const int w    = tid >> 6;        // wave 0..7
    const int quad = lane >> 4;       // 0..3
    const int lcol = lane & 15;       // 0..15
    const int bid  = blockIdx.x;
    const int team = bid >> 1;
    const int half = bid & 1;
    const int partner = bid ^ 1;
    const int b0 = team * 16;
    const int colbase = half * 256 + w * 32;

    // ---- persistent H B-fragments: hfrag[t][ks], lane holds H[col][k0..k0+7] ----
    short8 hfrag[2][16];
    #pragma unroll
    for (int t = 0; t < 2; ++t) {
        const float* hrow = H + (long)(colbase + t * 16 + lcol) * 512;
        #pragma unroll
        for (int ks = 0; ks < 16; ++ks) {
            const float* hp = hrow + ks * 32 + quad * 8;
            short8 fr;
            #pragma unroll
            for (int j = 0; j < 8; ++j) fr[j] = (short)f32_to_bf16(hp[j]);
            hfrag[t][ks] = fr;
        }
    }

    // ---- W = Phi[:64] @ Q ----
    for (int e = tid; e < 4096; e += 512) {
        int k = e >> 6, i = (e >> 3) & 7, l = e & 7;
        float s = 0.f;
        #pragma unroll
        for (int j = 0; j < 8; ++j) s += Phi[k * 64 + i * 8 + j] * Q[j * 8 + l];
        W[k][i * 8 + l] = s;
    }
    for (int e = tid; e < 16 * 520; e += 512) ((u16t*)u_bf)[e] = 0;
    __syncthreads();

    // ---- f (linear term) for my 16 rows x my 256 cols, C/D layout regs ----
    float f_reg[2][4], u_reg[2][4];
    #pragma unroll
    for (int t = 0; t < 2; ++t) {
        int c = colbase + t * 16 + lcol;
        int k = c >> 3, i = c & 7;
        #pragma unroll
        for (int r = 0; r < 4; ++r) {
            int m = quad * 4 + r;
            const float* xr = xref + (long)(b0 + m) * 65 * 8;
            float s = 0.f;
            #pragma unroll
            for (int l = 0; l < 8; ++l)
                s += W[k][i * 8 + l] * (xr[k * 8 + l] - xr[l]);
            f_reg[t][r] = -2.0f * s;
            u_reg[t][r] = 0.0f;
        }
    }

    u16t* mybuf0 = ubuf + ((long)bid * 2) * 4096;
    const u16t* pbuf0 = ubuf + ((long)partner * 2) * 4096;
    int* myflag = flags + bid * 16;
    int* pflag  = flags + partner * 16;
    const int pbase = (half ^ 1) * 256;

    for (int it = 0; it < 100; ++it) {
        floatx4 acc[2];
        acc[0] = (floatx4){0.f, 0.f, 0.f, 0.f};
        acc[1] = (floatx4){0.f, 0.f, 0.f, 0.f};

        #pragma unroll
        for (int ks = 0; ks < 16; ++ks) {
            int k0 = ks * 32 + quad * 8;
            short8 a = *(const short8*)&u_bf[lcol][k0];
            acc[0] = __builtin_amdgcn_mfma_f32_16x16x32_bf16(a, hfrag[0][ks], acc[0], 0, 0, 0);
            acc[1] = __builtin_amdgcn_mfma_f32_16x16x32_bf16(a, hfrag[1][ks], acc[1], 0, 0, 0);
        }

        // ---- update own half ----
        u16t nv[2][4];
        #pragma unroll
        for (int t = 0; t < 2; ++t)
            #pragma unroll
            for (int r = 0; r < 4; ++r) {
                float g  = acc[t][r] + f_reg[t][r];
                float un = u_reg[t][r] - 0.01f * g;
                un = fminf(1.0f, fmaxf(-1.0f, un));
                u_reg[t][r] = un;
                nv[t][r] = f32_to_bf16(un);
            }

        // ---- publish own half (agent-scope, IF$-coherent) ----
        const int buf = it & 1;
        u16t* dst = mybuf0 + buf * 4096;
        #pragma unroll
        for (int t = 0; t < 2; ++t)
            #pragma unroll
            for (int r = 0; r < 4; ++r) {
                int m = quad * 4 + r, cl = w * 32 + t * 16 + lcol;
                __hip_atomic_store(&dst[m * 256 + cl], nv[t][r],
                                   __ATOMIC_RELAXED, __HIP_MEMORY_SCOPE_AGENT);
            }
        __syncthreads();   // all u_bf reads done; all waves' sc1 stores drained (vmcnt0)
        if (tid == 0)
            __hip_atomic_store(myflag, it + 1, __ATOMIC_RELEASE, __HIP_MEMORY_SCOPE_AGENT);

        // ---- scatter own half into LDS ----
        #pragma unroll
        for (int t = 0; t < 2; ++t)
            #pragma unroll
            for (int r = 0; r < 4; ++r)
                u_bf[quad * 4 + r][colbase + t * 16 + lcol] = nv[t][r];

        // ---- wait for partner ----
        if (tid == 0) {
            int guard = 0;
            while (__hip_atomic_load(pflag, __ATOMIC_ACQUIRE, __HIP_MEMORY_SCOPE_AGENT) <= it) {
                if (++guard > (1 << 24)) break;   // hang-safety: fail loud, not forever
            }
        }
        __syncthreads();

        // ---- ingest partner half into LDS ----
        const unsigned* src32 = (const unsigned*)(pbuf0 + buf * 4096);
        #pragma unroll
        for (int q = 0; q < 4; ++q) {
            int d = q * 512 + tid;                 // 0..2047 dwords, coalesced
            unsigned v = __hip_atomic_load(&src32[d], __ATOMIC_RELAXED, __HIP_MEMORY_SCOPE_AGENT);
            int m = d >> 7, cp = (d & 127) * 2;
            *(unsigned*)&u_bf[m][pbase + cp] = v;
        }
        __syncthreads();
    }

    // ---- write final u (fp32), own 16 rows x 256 cols ----
    #pragma unroll
    for (int t = 0; t < 2; ++t)
        #pragma unroll
        for (int r = 0; r < 4; ++r)
            out[(long)(b0 + quad * 4 + r) * 512 + colbase + t * 16 + lcol] = u_reg[t][r];
}

extern "C" void kernel_launch(void* const* d_in, const int* in_sizes, int n_in,
                              void* d_out, int out_size, void* d_ws, size_t ws_size,
                              hipStream_t stream) {
    // inputs: 0=x0 (unused), 1=xref, 2=H, 3=Phi, 4=Q
    const float* xref = (const float*)d_in[1];
    const float* H    = (const float*)d_in[2];
    const float* Phi  = (const float*)d_in[3];
    const float* Q    = (const float*)d_in[4];

    int*  flags = (int*)d_ws;                                  // 16 KB
    u16t* ubuf  = (u16t*)((char*)d_ws + 256 * 16 * sizeof(int)); // 4 MB

    init_flags_kernel<<<1, 256, 0, stream>>>(flags);
    pgd_pair_kernel<<<256, 512, 0, stream>>>(xref, H, Phi, Q, (float*)d_out, flags, ubuf);
}

// Round 3
// 787.158 us; speedup vs baseline: 1.0951x; 1.0951x over previous
//
#include <hip/hip_runtime.h>

// LinearMPC PGD, round 3: H mostly register-stationary, single-block-per-rowgroup.
// 128 blocks x 256 thr (4 waves, 1 wave/SIMD, 512 unified VGPR budget).
// Wave w owns cols [w*128, +128) = 8 MFMA n-tiles; tiles 0..5 held as bf16
// B-fragments in registers (384 regs), tiles 6..7 streamed from L2 (128 KB/CU/iter
// vs round-1's 512 KB -> 4x less of the binding per-CU L2 ingress).
// No cross-block communication (round-2 lesson: coherence round-trips cost ~8us/iter).

typedef unsigned short u16t;
typedef __attribute__((ext_vector_type(8))) short short8;
typedef __attribute__((ext_vector_type(4))) float floatx4;

__device__ __forceinline__ u16t f32_to_bf16(float x) {
    unsigned int u = __builtin_bit_cast(unsigned int, x);
    u = (u + 0x7FFFu + ((u >> 16) & 1u)) >> 16;   // RNE
    return (u16t)u;
}

__global__ void convert_H_bf16(const float* __restrict__ H, u16t* __restrict__ Hb) {
    int idx = blockIdx.x * 256 + threadIdx.x;   // 1024 x 256 = 262144
    Hb[idx] = f32_to_bf16(H[idx]);
}

#define MFMA(a, b, c) __builtin_amdgcn_mfma_f32_16x16x32_bf16((a), (b), (c), 0, 0, 0)

__global__ __launch_bounds__(256, 1)
void pgd_reg_kernel(const float* __restrict__ xref,   // [2048][65][8]
                    const float* __restrict__ H,      // [512][512] fp32
                    const u16t*  __restrict__ Hb,     // [512][512] bf16
                    const float* __restrict__ Phi,    // [65][8][8]
                    const float* __restrict__ Q,      // [8][8]
                    float* __restrict__ out)          // [2048][512]
{
    __shared__ __align__(16) u16t u_bf[16][520];   // pad 520: b128 reads ~conflict-free
    __shared__ float f_lds[16][512];               // thread-private slots (same thread rw)

    const int tid  = threadIdx.x;
    const int lane = tid & 63;
    const int w    = tid >> 6;        // wave 0..3
    const int quad = lane >> 4;       // 0..3
    const int lcol = lane & 15;       // 0..15
    const int b0   = blockIdx.x * 16;
    const int colbase = w * 128;

    // ---- persistent B-fragments for tiles 0..5 (384 VGPR/AGPRs) ----
    short8 hfrag[6][16];
    #pragma unroll
    for (int t = 0; t < 6; ++t) {
        const float* hrow = H + (long)(colbase + t * 16 + lcol) * 512;
        #pragma unroll
        for (int ks = 0; ks < 16; ++ks) {
            const float* hp = hrow + ks * 32 + quad * 8;
            short8 fr;
            #pragma unroll
            for (int j = 0; j < 8; ++j) fr[j] = (short)f32_to_bf16(hp[j]);
            hfrag[t][ks] = fr;
        }
    }

    // ---- zero u_bf ----
    for (int e = tid; e < 16 * 520; e += 256) ((u16t*)u_bf)[e] = 0;

    // ---- f into LDS (each thread writes exactly the slots it later reads) ----
    #pragma unroll
    for (int T = 0; T < 8; ++T) {
        int c = colbase + T * 16 + lcol;
        int k = c >> 3, i = c & 7;
        #pragma unroll
        for (int r = 0; r < 4; ++r) {
            int m = quad * 4 + r;
            const float* xr = xref + (long)(b0 + m) * 520;
            float dx[8];
            #pragma unroll
            for (int l = 0; l < 8; ++l) dx[l] = xr[k * 8 + l] - xr[l];
            float s = 0.f;
            #pragma unroll
            for (int j = 0; j < 8; ++j) {
                float z = 0.f;
                #pragma unroll
                for (int l = 0; l < 8; ++l) z += Q[j * 8 + l] * dx[l];
                s += Phi[k * 64 + i * 8 + j] * z;
            }
            f_lds[m][c] = -2.0f * s;
        }
    }

    float u_reg[8][4];
    #pragma unroll
    for (int T = 0; T < 8; ++T)
        #pragma unroll
        for (int r = 0; r < 4; ++r) u_reg[T][r] = 0.f;

    __syncthreads();

    const u16t* hb6 = Hb + (long)(colbase + 6 * 16 + lcol) * 512;
    const u16t* hb7 = Hb + (long)(colbase + 7 * 16 + lcol) * 512;

    for (int it = 0; it < 100; ++it) {
        // ======== pass A: reg tiles 0,1,2 + streamed tile 6 ========
        {
            floatx4 acc[4];
            #pragma unroll
            for (int tt = 0; tt < 4; ++tt) acc[tt] = (floatx4){0.f, 0.f, 0.f, 0.f};
            short8 bc = *(const short8*)&hb6[quad * 8];
            short8 b1 = *(const short8*)&hb6[32 + quad * 8];
            #pragma unroll
            for (int ks = 0; ks < 16; ++ks) {
                short8 bn = (ks < 14) ? *(const short8*)&hb6[(ks + 2) * 32 + quad * 8] : b1;
                short8 a  = *(const short8*)&u_bf[lcol][ks * 32 + quad * 8];
                acc[0] = MFMA(a, hfrag[0][ks], acc[0]);
                acc[1] = MFMA(a, hfrag[1][ks], acc[1]);
                acc[2] = MFMA(a, hfrag[2][ks], acc[2]);
                acc[3] = MFMA(a, bc, acc[3]);
                bc = b1; b1 = bn;
            }
            #pragma unroll
            for (int tt = 0; tt < 4; ++tt) {
                const int T = (tt < 3) ? tt : 6;
                int c = colbase + T * 16 + lcol;
                #pragma unroll
                for (int r = 0; r < 4; ++r) {
                    int m = quad * 4 + r;
                    float g  = acc[tt][r] + f_lds[m][c];
                    float un = u_reg[T][r] - 0.01f * g;
                    un = fminf(1.0f, fmaxf(-1.0f, un));
                    u_reg[T][r] = un;
                }
            }
        }
        // ======== pass B: reg tiles 3,4,5 + streamed tile 7 ========
        {
            floatx4 acc[4];
            #pragma unroll
            for (int tt = 0; tt < 4; ++tt) acc[tt] = (floatx4){0.f, 0.f, 0.f, 0.f};
            short8 bc = *(const short8*)&hb7[quad * 8];
            short8 b1 = *(const short8*)&hb7[32 + quad * 8];
            #pragma unroll
            for (int ks = 0; ks < 16; ++ks) {
                short8 bn = (ks < 14) ? *(const short8*)&hb7[(ks + 2) * 32 + quad * 8] : b1;
                short8 a  = *(const short8*)&u_bf[lcol][ks * 32 + quad * 8];
                acc[0] = MFMA(a, hfrag[3][ks], acc[0]);
                acc[1] = MFMA(a, hfrag[4][ks], acc[1]);
                acc[2] = MFMA(a, hfrag[5][ks], acc[2]);
                acc[3] = MFMA(a, bc, acc[3]);
                bc = b1; b1 = bn;
            }
            #pragma unroll
            for (int tt = 0; tt < 4; ++tt) {
                const int T = (tt < 3) ? tt + 3 : 7;
                int c = colbase + T * 16 + lcol;
                #pragma unroll
                for (int r = 0; r < 4; ++r) {
                    int m = quad * 4 + r;
                    float g  = acc[tt][r] + f_lds[m][c];
                    float un = u_reg[T][r] - 0.01f * g;
                    un = fminf(1.0f, fmaxf(-1.0f, un));
                    u_reg[T][r] = un;
                }
            }
        }
        __syncthreads();   // all waves done reading old u_bf
        #pragma unroll
        for (int T = 0; T < 8; ++T) {
            int c = colbase + T * 16 + lcol;
            #pragma unroll
            for (int r = 0; r < 4; ++r)
                u_bf[quad * 4 + r][c] = f32_to_bf16(u_reg[T][r]);
        }
        __syncthreads();   // new u_bf visible
    }

    // ---- write final u (fp32) ----
    #pragma unroll
    for (int T = 0; T < 8; ++T) {
        int c = colbase + T * 16 + lcol;
        #pragma unroll
        for (int r = 0; r < 4; ++r)
            out[(long)(b0 + quad * 4 + r) * 512 + c] = u_reg[T][r];
    }
}

extern "C" void kernel_launch(void* const* d_in, const int* in_sizes, int n_in,
                              void* d_out, int out_size, void* d_ws, size_t ws_size,
                              hipStream_t stream) {
    // inputs: 0=x0 (unused), 1=xref, 2=H, 3=Phi, 4=Q
    const float* xref = (const float*)d_in[1];
    const float* H    = (const float*)d_in[2];
    const float* Phi  = (const float*)d_in[3];
    const float* Q    = (const float*)d_in[4];
    u16t* Hb = (u16t*)d_ws;                      // 512 KB

    convert_H_bf16<<<1024, 256, 0, stream>>>(H, Hb);
    pgd_reg_kernel<<<128, 256, 0, stream>>>(xref, H, Hb, Phi, Q, (float*)d_out);
}

// Round 4
// 268.503 us; speedup vs baseline: 3.2104x; 2.9317x over previous
//
#include <hip/hip_runtime.h>

// LinearMPC PGD, round 4: three-tier H residency (regs + LDS + L2 stream).
// 128 blocks x 512 thr (8 waves, 2/SIMD, 256 VGPR/wave cap respected).
// Wave w owns cols [w*64,+64) = 4 MFMA n-tiles:
//   T0,T1: bf16 B-fragments in registers (128 VGPRs/wave, 256 H-rows/CU)
//   T2:    H rows in LDS (128 rows, 133 KB, iteration-invariant, ds_read_b128)
//   T3:    streamed from L2 each iter (128 KB/CU/iter vs round-1's 512 KB)
// Round-3 lesson: arch VGPRs cap at 256 -> never plan >2 resident tiles/wave.
// Round-2 lesson: no cross-block per-iteration communication.

typedef unsigned short u16t;
typedef __attribute__((ext_vector_type(8))) short short8;
typedef __attribute__((ext_vector_type(4))) float floatx4;

#define HLDS_BYTES (128 * 520 * 2)                 // 133,120
#define UBF_BYTES  (16 * 520 * 2)                  // 16,640
#define DYN_LDS    (HLDS_BYTES + UBF_BYTES)        // 149,760 < 160 KiB

__device__ __forceinline__ u16t f32_to_bf16(float x) {
    unsigned int u = __builtin_bit_cast(unsigned int, x);
    u = (u + 0x7FFFu + ((u >> 16) & 1u)) >> 16;   // RNE
    return (u16t)u;
}

__global__ void convert_H_bf16(const float* __restrict__ H, u16t* __restrict__ Hb) {
    int idx = blockIdx.x * 256 + threadIdx.x;   // 1024 x 256 = 262144
    Hb[idx] = f32_to_bf16(H[idx]);
}

#define MFMA(a, b, c) __builtin_amdgcn_mfma_f32_16x16x32_bf16((a), (b), (c), 0, 0, 0)

__global__ __launch_bounds__(512, 2)
void pgd_hybrid_kernel(const float* __restrict__ xref,   // [2048][65][8]
                       const float* __restrict__ H,      // [512][512] fp32
                       const u16t*  __restrict__ Hb,     // [512][512] bf16
                       const float* __restrict__ Phi,    // [65][8][8]
                       const float* __restrict__ Q,      // [8][8]
                       float* __restrict__ out)          // [2048][512]
{
    extern __shared__ __align__(16) char smem[];
    u16t* Hlds = (u16t*)smem;                          // [128][520] (row pad +8)
    u16t (*u_bf)[520] = (u16t(*)[520])(smem + HLDS_BYTES);  // [16][520]

    const int tid  = threadIdx.x;
    const int lane = tid & 63;
    const int w    = tid >> 6;        // wave 0..7
    const int quad = lane >> 4;       // 0..3
    const int lcol = lane & 15;       // 0..15
    const int b0   = blockIdx.x * 16;
    const int colbase = w * 64;

    // ---- stage T2 H-rows into LDS: ldsrow r holds H[(r>>4)*64 + 32 + (r&15)] ----
    for (int e = tid; e < 8192; e += 512) {           // 16 iters of 16B
        int r = e >> 6, c = e & 63;
        *(short8*)&Hlds[r * 520 + c * 8] =
            *(const short8*)&Hb[(long)((r >> 4) * 64 + 32 + (r & 15)) * 512 + c * 8];
    }
    // ---- zero u_bf ----
    {
        u16t* ub = &u_bf[0][0];
        for (int e = tid; e < 8320; e += 512) ub[e] = 0;
    }

    // ---- persistent register B-fragments: tiles T0,T1 (128 VGPRs/wave) ----
    short8 hfrag[2][16];
    #pragma unroll
    for (int t = 0; t < 2; ++t) {
        const float* hrow = H + (long)(colbase + t * 16 + lcol) * 512;
        #pragma unroll
        for (int ks = 0; ks < 16; ++ks) {
            const float* hp = hrow + ks * 32 + quad * 8;
            short8 fr;
            #pragma unroll
            for (int j = 0; j < 8; ++j) fr[j] = (short)f32_to_bf16(hp[j]);
            hfrag[t][ks] = fr;
        }
    }

    // ---- f (linear term) + u master, per-thread regs, C/D layout ----
    float f_reg[4][4], u_reg[4][4];
    #pragma unroll
    for (int T = 0; T < 4; ++T) {
        int c = colbase + T * 16 + lcol;
        int k = c >> 3, i = c & 7;
        #pragma unroll
        for (int r = 0; r < 4; ++r) {
            int m = quad * 4 + r;
            const float* xr = xref + (long)(b0 + m) * 520;
            float s = 0.f;
            #pragma unroll
            for (int j = 0; j < 8; ++j) {
                float z = 0.f;
                #pragma unroll
                for (int l = 0; l < 8; ++l) z += Q[j * 8 + l] * (xr[k * 8 + l] - xr[l]);
                s += Phi[k * 64 + i * 8 + j] * z;
            }
            f_reg[T][r] = -2.0f * s;
            u_reg[T][r] = 0.0f;
        }
    }
    __syncthreads();

    // streamed tile T3 base (global col w*64+48+lcol), iteration-invariant
    const u16t* hb3 = Hb + (long)(colbase + 48 + lcol) * 512;
    const u16t* h2  = Hlds + (w * 16 + lcol) * 520;

    // rolling +2 prefetch of T3 fragments (wraps across iterations; addrs invariant)
    short8 s0 = *(const short8*)&hb3[quad * 8];
    short8 s1 = *(const short8*)&hb3[32 + quad * 8];

    for (int it = 0; it < 100; ++it) {
        floatx4 acc[4];
        #pragma unroll
        for (int T = 0; T < 4; ++T) acc[T] = (floatx4){0.f, 0.f, 0.f, 0.f};

        #pragma unroll
        for (int ks = 0; ks < 16; ++ks) {
            short8 a  = *(const short8*)&u_bf[lcol][ks * 32 + quad * 8];
            short8 b2 = *(const short8*)&h2[ks * 32 + quad * 8];
            short8 b3 = s0;
            s0 = s1;
            s1 = *(const short8*)&hb3[(((ks + 2) & 15) * 32 + quad * 8)];
            acc[0] = MFMA(a, hfrag[0][ks], acc[0]);
            acc[1] = MFMA(a, hfrag[1][ks], acc[1]);
            acc[2] = MFMA(a, b2, acc[2]);
            acc[3] = MFMA(a, b3, acc[3]);
        }

        // ---- update u ----
        u16t nv[4][4];
        #pragma unroll
        for (int T = 0; T < 4; ++T)
            #pragma unroll
            for (int r = 0; r < 4; ++r) {
                float g  = acc[T][r] + f_reg[T][r];
                float un = u_reg[T][r] - 0.01f * g;
                un = fminf(1.0f, fmaxf(-1.0f, un));
                u_reg[T][r] = un;
                nv[T][r] = f32_to_bf16(un);
            }

        __syncthreads();   // all waves done reading old u_bf
        #pragma unroll
        for (int T = 0; T < 4; ++T) {
            int c = colbase + T * 16 + lcol;
            #pragma unroll
            for (int r = 0; r < 4; ++r)
                u_bf[quad * 4 + r][c] = nv[T][r];
        }
        __syncthreads();   // new u_bf visible
    }

    // ---- write final u (fp32) ----
    #pragma unroll
    for (int T = 0; T < 4; ++T) {
        int c = colbase + T * 16 + lcol;
        #pragma unroll
        for (int r = 0; r < 4; ++r)
            out[(long)(b0 + quad * 4 + r) * 512 + c] = u_reg[T][r];
    }
}

extern "C" void kernel_launch(void* const* d_in, const int* in_sizes, int n_in,
                              void* d_out, int out_size, void* d_ws, size_t ws_size,
                              hipStream_t stream) {
    // inputs: 0=x0 (unused), 1=xref, 2=H, 3=Phi, 4=Q
    const float* xref = (const float*)d_in[1];
    const float* H    = (const float*)d_in[2];
    const float* Phi  = (const float*)d_in[3];
    const float* Q    = (const float*)d_in[4];
    u16t* Hb = (u16t*)d_ws;                      // 512 KB

    // allow 149.76 KB dynamic LDS (gfx950: 160 KiB/CU); idempotent, non-stream call
    static int attr_done = 0;
    (void)hipFuncSetAttribute((const void*)pgd_hybrid_kernel,
                              hipFuncAttributeMaxDynamicSharedMemorySize, DYN_LDS);
    (void)attr_done;

    convert_H_bf16<<<1024, 256, 0, stream>>>(H, Hb);
    pgd_hybrid_kernel<<<128, 512, DYN_LDS, stream>>>(xref, H, Hb, Phi, Q, (float*)d_out);
}

// Round 5
// 253.940 us; speedup vs baseline: 3.3945x; 1.0573x over previous
//
#include <hip/hip_runtime.h>

// LinearMPC PGD, round 5: 2.5-tier H residency.
// 128 blocks x 512 thr (8 waves, 2/SIMD, <=256 unified regs/wave).
// Wave w owns cols [w*64,+64) = 4 MFMA n-tiles:
//   T0,T1: bf16 B-fragments in registers (128 regs)
//   T2:    H rows in LDS (128 rows/CU, 133 KB, iteration-invariant)
//   T3:    ks 0..7 in registers (32 regs), ks 8..15 streamed from L2
//          (64 KB/CU/iter, half of round 4's stream)
// Lessons: R2 no cross-block comm; R3 arch VGPR cap 256 (spill => WRITE_SIZE blowup);
// R4 pipes only partially overlap -> cut the L2 stream, LDS is the structural floor.

typedef unsigned short u16t;
typedef __attribute__((ext_vector_type(8))) short short8;
typedef __attribute__((ext_vector_type(4))) float floatx4;

#define HLDS_BYTES (128 * 520 * 2)                 // 133,120
#define UBF_BYTES  (16 * 520 * 2)                  // 16,640
#define DYN_LDS    (HLDS_BYTES + UBF_BYTES)        // 149,760 < 160 KiB

__device__ __forceinline__ u16t f32_to_bf16(float x) {
    unsigned int u = __builtin_bit_cast(unsigned int, x);
    u = (u + 0x7FFFu + ((u >> 16) & 1u)) >> 16;   // RNE
    return (u16t)u;
}

__global__ void convert_H_bf16(const float* __restrict__ H, u16t* __restrict__ Hb) {
    int idx = blockIdx.x * 256 + threadIdx.x;   // 1024 x 256 = 262144
    Hb[idx] = f32_to_bf16(H[idx]);
}

#define MFMA(a, b, c) __builtin_amdgcn_mfma_f32_16x16x32_bf16((a), (b), (c), 0, 0, 0)

__global__ __launch_bounds__(512, 2)
void pgd_kernel5(const float* __restrict__ xref,   // [2048][65][8]
                 const float* __restrict__ H,      // [512][512] fp32
                 const u16t*  __restrict__ Hb,     // [512][512] bf16
                 const float* __restrict__ Phi,    // [65][8][8]
                 const float* __restrict__ Q,      // [8][8]
                 float* __restrict__ out)          // [2048][512]
{
    extern __shared__ __align__(16) char smem[];
    u16t* Hlds = (u16t*)smem;                               // [128][520]
    u16t (*u_bf)[520] = (u16t(*)[520])(smem + HLDS_BYTES);  // [16][520]

    const int tid  = threadIdx.x;
    const int lane = tid & 63;
    const int w    = tid >> 6;        // wave 0..7
    const int quad = lane >> 4;       // 0..3
    const int lcol = lane & 15;       // 0..15
    const int b0   = blockIdx.x * 16;
    const int colbase = w * 64;

    // ---- stage T2 H-rows into LDS: ldsrow r holds H[(r>>4)*64 + 32 + (r&15)] ----
    for (int e = tid; e < 8192; e += 512) {
        int r = e >> 6, c = e & 63;
        *(short8*)&Hlds[r * 520 + c * 8] =
            *(const short8*)&Hb[(long)((r >> 4) * 64 + 32 + (r & 15)) * 512 + c * 8];
    }
    // ---- zero u_bf ----
    {
        u16t* ub = &u_bf[0][0];
        for (int e = tid; e < 8320; e += 512) ub[e] = 0;
    }

    // ---- register B-fragments: T0,T1 full (128 regs) ----
    short8 hfragA[2][16];
    #pragma unroll
    for (int t = 0; t < 2; ++t) {
        const float* hrow = H + (long)(colbase + t * 16 + lcol) * 512;
        #pragma unroll
        for (int ks = 0; ks < 16; ++ks) {
            const float* hp = hrow + ks * 32 + quad * 8;
            short8 fr;
            #pragma unroll
            for (int j = 0; j < 8; ++j) fr[j] = (short)f32_to_bf16(hp[j]);
            hfragA[t][ks] = fr;
        }
    }
    // ---- register B-fragments: T3 ks 0..7 (32 regs) ----
    short8 frag3[8];
    {
        const float* hrow = H + (long)(colbase + 48 + lcol) * 512;
        #pragma unroll
        for (int ks = 0; ks < 8; ++ks) {
            const float* hp = hrow + ks * 32 + quad * 8;
            short8 fr;
            #pragma unroll
            for (int j = 0; j < 8; ++j) fr[j] = (short)f32_to_bf16(hp[j]);
            frag3[ks] = fr;
        }
    }

    // ---- f (linear term) + u master, per-thread regs, C/D layout ----
    float f_reg[4][4], u_reg[4][4];
    #pragma unroll
    for (int T = 0; T < 4; ++T) {
        int c = colbase + T * 16 + lcol;
        int k = c >> 3, i = c & 7;
        #pragma unroll
        for (int r = 0; r < 4; ++r) {
            int m = quad * 4 + r;
            const float* xr = xref + (long)(b0 + m) * 520;
            float s = 0.f;
            #pragma unroll
            for (int j = 0; j < 8; ++j) {
                float z = 0.f;
                #pragma unroll
                for (int l = 0; l < 8; ++l) z += Q[j * 8 + l] * (xr[k * 8 + l] - xr[l]);
                s += Phi[k * 64 + i * 8 + j] * z;
            }
            f_reg[T][r] = -2.0f * s;
            u_reg[T][r] = 0.0f;
        }
    }
    __syncthreads();

    // streamed half of T3: ks 8..15 of row (colbase+48+lcol), iteration-invariant
    const u16t* hb3 = Hb + (long)(colbase + 48 + lcol) * 512;
    const u16t* h2  = Hlds + (w * 16 + lcol) * 520;

    // rolling +2 prefetch (wraps across iterations; addresses invariant)
    short8 sb0 = *(const short8*)&hb3[8 * 32 + quad * 8];
    short8 sb1 = *(const short8*)&hb3[9 * 32 + quad * 8];

    for (int it = 0; it < 100; ++it) {
        floatx4 acc[4];
        #pragma unroll
        for (int T = 0; T < 4; ++T) acc[T] = (floatx4){0.f, 0.f, 0.f, 0.f};

        // ---- ks 0..7: all-register T3 ----
        #pragma unroll
        for (int ks = 0; ks < 8; ++ks) {
            short8 a  = *(const short8*)&u_bf[lcol][ks * 32 + quad * 8];
            short8 b2 = *(const short8*)&h2[ks * 32 + quad * 8];
            acc[0] = MFMA(a, hfragA[0][ks], acc[0]);
            acc[1] = MFMA(a, hfragA[1][ks], acc[1]);
            acc[2] = MFMA(a, b2, acc[2]);
            acc[3] = MFMA(a, frag3[ks], acc[3]);
        }
        // ---- ks 8..15: streamed T3 ----
        #pragma unroll
        for (int ks = 8; ks < 16; ++ks) {
            short8 a  = *(const short8*)&u_bf[lcol][ks * 32 + quad * 8];
            short8 b2 = *(const short8*)&h2[ks * 32 + quad * 8];
            short8 b3 = sb0;
            sb0 = sb1;
            sb1 = *(const short8*)&hb3[(8 + ((ks - 6) & 7)) * 32 + quad * 8];
            acc[0] = MFMA(a, hfragA[0][ks], acc[0]);
            acc[1] = MFMA(a, hfragA[1][ks], acc[1]);
            acc[2] = MFMA(a, b2, acc[2]);
            acc[3] = MFMA(a, b3, acc[3]);
        }

        // ---- update u master ----
        #pragma unroll
        for (int T = 0; T < 4; ++T)
            #pragma unroll
            for (int r = 0; r < 4; ++r) {
                float g  = acc[T][r] + f_reg[T][r];
                float un = u_reg[T][r] - 0.01f * g;
                un = fminf(1.0f, fmaxf(-1.0f, un));
                u_reg[T][r] = un;
            }

        __syncthreads();   // all waves done reading old u_bf
        #pragma unroll
        for (int T = 0; T < 4; ++T) {
            int c = colbase + T * 16 + lcol;
            #pragma unroll
            for (int r = 0; r < 4; ++r)
                u_bf[quad * 4 + r][c] = f32_to_bf16(u_reg[T][r]);
        }
        __syncthreads();   // new u_bf visible
    }

    // ---- write final u (fp32) ----
    #pragma unroll
    for (int T = 0; T < 4; ++T) {
        int c = colbase + T * 16 + lcol;
        #pragma unroll
        for (int r = 0; r < 4; ++r)
            out[(long)(b0 + quad * 4 + r) * 512 + c] = u_reg[T][r];
    }
}

extern "C" void kernel_launch(void* const* d_in, const int* in_sizes, int n_in,
                              void* d_out, int out_size, void* d_ws, size_t ws_size,
                              hipStream_t stream) {
    // inputs: 0=x0 (unused), 1=xref, 2=H, 3=Phi, 4=Q
    const float* xref = (const float*)d_in[1];
    const float* H    = (const float*)d_in[2];
    const float* Phi  = (const float*)d_in[3];
    const float* Q    = (const float*)d_in[4];
    u16t* Hb = (u16t*)d_ws;                      // 512 KB

    (void)hipFuncSetAttribute((const void*)pgd_kernel5,
                              hipFuncAttributeMaxDynamicSharedMemorySize, DYN_LDS);

    convert_H_bf16<<<1024, 256, 0, stream>>>(H, Hb);
    pgd_kernel5<<<128, 512, DYN_LDS, stream>>>(xref, H, Hb, Phi, Q, (float*)d_out);
}